// Round 9
// baseline (416.903 us; speedup 1.0000x reference)
//
#include <hip/hip_runtime.h>

// 2-layer GCN via bucketed counting sort + split-K LDS aggregation.
// R22 = R21 with ONE change: ATOMIC-FREE SCATTER via rank recycling.
// Model (confirmed R20/R21): every edge-pass is bound by ~3.4 cy per LDS
// RMW instruction-lane per CU (width/flavor/address independent); passes
// sit near a ~46us/pass floor. Budget was count 1 + scatter 1 + deg 1 +
// agg1 1 + agg2 1 = 5 RMW/edge. The count pass's atomicAdd RETURN VALUE is
// exactly the rank scatter re-derives with its own atomic -> persist it:
//   count: rank16[e] = rank within (block, bucket, subhist)  (u16, <32768)
//          subPre[blk][bucket] = int4 prefix of the 4 sub-hists (960KB)
//   scatter: pos = bucketPtr[b] + histM[b][blk] + subPre[b][sub] + rank16[e]
//            -> ZERO atomics, pure stream + scattered store.
// 5 -> 4 RMW/edge at +32MB of rank traffic (~5us BW).
// Prediction: scatter 72 -> 30-40us (bank-conflict counter -> ~0), count
// ~+5us, total 337 -> ~300-312us. Falsifier: scatter >= 55us atomic-free
// => scattered 4B stores are the wall => LDS store-combining next.
// Edge record u32: rec = (src<<11) | (dst&2047)  (src < 2^19).
//
// Pipeline (LDS atomics only; scatter now atomic-free):
//   A  bucket_count   : LDS hist (4-way sub-hist) -> histM, rank16, subPre
//   B1 colscan        : exclusive scan of histM rows + totals
//   B2 bucketscan     : exclusive scan of totals -> bucketPtr
//   C  bucket_scatter : pos from precomputed ranks; store rec
//   D1 deg_partial    : split-K LDS hist -> partialD[sp][node]
//   D2 deg_xd         : deg -> degA; thp = packed 3x21b fixed point
//   E1 agg1_partial   : split-K LDS accum, ONE ds_add_u64 per edge
//   E2 z_epilogue     : decode partials + fp32 self; W1+ReLU+W2 -> z
//   F1 agg2_partial   : split-K LDS u64 fixed-point accum of z[src]
//   F2 out_epilogue   : decode partials + self -> out

#define SHIFT 11
#define BSZ   2048             // nodes per bucket
#define CH    32768            // edges per block in passes A/C
#define AC_THREADS 512
#define NBK_MAX 256
#define AGG_THREADS 512
#define SPLIT 4                // sub-blocks per bucket in D1/E1/F1

// layer-1 packed encoding: 3 fields x 21 bits
#define S1F  4096.0f           // 2^12
#define IS1F (1.0f/4096.0f)
#define B1   16384             // 2^14 bias per term
#define CLV1 3.999f
#define FMASK 0x1FFFFFu

// layer-2 encoding: 2 fields x 32 bits
#define S2F  131072.0f         // 2^17
#define IS2F (1.0f/131072.0f)
#define BI2  (1<<22)
#define CLV2 15.0f

typedef float vfloat4 __attribute__((ext_vector_type(4)));
typedef unsigned int vuint4 __attribute__((ext_vector_type(4)));

union H4 { uint2 u; _Float16 h[4]; };

__device__ __forceinline__ int ntload_i(const int* p) { return __builtin_nontemporal_load(p); }
__device__ __forceinline__ unsigned int ntload_u(const unsigned int* p) { return __builtin_nontemporal_load(p); }
__device__ __forceinline__ unsigned short ntload_u16(const unsigned short* p) { return __builtin_nontemporal_load(p); }
__device__ __forceinline__ unsigned long long ntload_u64(const unsigned long long* p) {
    return __builtin_nontemporal_load(p);
}
__device__ __forceinline__ void ntstore_u64(unsigned long long v, unsigned long long* p) {
    __builtin_nontemporal_store(v, p);
}

// A: per-block 4-way sub-histogram; persists per-edge rank (u16) and the
// per-(block,bucket) sub-hist prefix (int4) so scatter needs no atomics.
__global__ void bucket_count_kernel(const int* __restrict__ dst, int* __restrict__ histM,
                                    unsigned short* __restrict__ rank16,
                                    int4* __restrict__ subPre,
                                    int E, int NBA, int NBK) {
    __shared__ int lhist[4 * NBK_MAX];
    int t = threadIdx.x;
    for (int b = t; b < 4 * NBK; b += AC_THREADS) lhist[b] = 0;
    __syncthreads();
    int sub = t & 3;
    int base = blockIdx.x * CH;
#pragma unroll 8
    for (int k = 0; k < CH / AC_THREADS; ++k) {
        int e = base + t + k * AC_THREADS;
        if (e < E) {
            int r = atomicAdd(&lhist[((ntload_i(&dst[e]) >> SHIFT) << 2) | sub], 1);
            __builtin_nontemporal_store((unsigned short)r, &rank16[e]);
        }
    }
    __syncthreads();
    for (int b = t; b < NBK; b += AC_THREADS) {
        int c0 = lhist[4 * b], c1 = lhist[4 * b + 1], c2 = lhist[4 * b + 2], c3 = lhist[4 * b + 3];
        histM[(size_t)b * NBA + blockIdx.x] = c0 + c1 + c2 + c3;
        subPre[(size_t)blockIdx.x * NBK + b] = make_int4(0, c0, c0 + c1, c0 + c1 + c2);
    }
}

// Exclusive scan of one bucket's row histM[bk][0..NBA-1] in place; totals[bk]=sum.
__global__ void colscan_kernel(int* __restrict__ histM, int* __restrict__ totals,
                               int NBA) {
    __shared__ int sdata[256];
    int t = threadIdx.x;
    size_t base = (size_t)blockIdx.x * NBA;
    int v[4];
#pragma unroll
    for (int k = 0; k < 4; ++k) { int i = t * 4 + k; v[k] = (i < NBA) ? histM[base + i] : 0; }
    int s = v[0] + v[1] + v[2] + v[3];
    sdata[t] = s;
    __syncthreads();
    for (int off = 1; off < 256; off <<= 1) {
        int xv = (t >= off) ? sdata[t - off] : 0;
        __syncthreads();
        sdata[t] += xv;
        __syncthreads();
    }
    if (t == 255) totals[blockIdx.x] = sdata[255];
    int run = sdata[t] - s;
#pragma unroll
    for (int k = 0; k < 4; ++k) { int i = t * 4 + k; if (i < NBA) histM[base + i] = run; run += v[k]; }
}

// Exclusive scan of totals[NBK] -> bucketPtr; bucketPtr[NBK]=E.
__global__ void bucketscan_kernel(const int* __restrict__ totals, int* __restrict__ bucketPtr,
                                  int NBK, int E) {
    __shared__ int sdata[256];
    int t = threadIdx.x;
    int v[4];
#pragma unroll
    for (int k = 0; k < 4; ++k) { int i = t * 4 + k; v[k] = (i < NBK) ? totals[i] : 0; }
    int s = v[0] + v[1] + v[2] + v[3];
    sdata[t] = s;
    __syncthreads();
    for (int off = 1; off < 256; off <<= 1) {
        int xv = (t >= off) ? sdata[t - off] : 0;
        __syncthreads();
        sdata[t] += xv;
        __syncthreads();
    }
    int run = sdata[t] - s;
#pragma unroll
    for (int k = 0; k < 4; ++k) { int i = t * 4 + k; if (i < NBK) bucketPtr[i] = run; run += v[k]; }
    if (t == 255) bucketPtr[NBK] = E;
}

// C: atomic-free scatter. pos = cur[b] + sp[4b+sub] + rank16[e].
// Thread->edge mapping identical to count (same base + t + k*AC_THREADS),
// so sub = t&3 reproduces count's sub-hist assignment exactly.
__global__ void bucket_scatter_kernel(const int* __restrict__ ei, const int* __restrict__ histM,
                                      const int* __restrict__ bucketPtr,
                                      const unsigned short* __restrict__ rank16,
                                      const int4* __restrict__ subPre,
                                      unsigned int* __restrict__ sorted,
                                      int E, int NBA, int NBK) {
    __shared__ int cur[NBK_MAX];
    __shared__ int sp[4 * NBK_MAX];
    int t = threadIdx.x;
    for (int b = t; b < NBK; b += AC_THREADS)
        cur[b] = bucketPtr[b] + histM[(size_t)b * NBA + blockIdx.x];
    const int* spf = (const int*)(subPre + (size_t)blockIdx.x * NBK);
    for (int i = t; i < 4 * NBK; i += AC_THREADS) sp[i] = spf[i];
    __syncthreads();
    int sub = t & 3;
    int base = blockIdx.x * CH;
#pragma unroll 8
    for (int k = 0; k < CH / AC_THREADS; ++k) {
        int e = base + t + k * AC_THREADS;
        if (e < E) {
            int s = ntload_i(&ei[e]);
            int d = ntload_i(&ei[E + e]);
            int b = d >> SHIFT;
            int pos = cur[b] + sp[4 * b + sub] + (int)ntload_u16(&rank16[e]);
            sorted[pos] = ((unsigned int)s << SHIFT) | (unsigned int)(d & (BSZ - 1));
        }
    }
}

// D1: split-K per-node degree histogram -> partialD[sp][node].
__global__ void deg_partial_kernel(const unsigned int* __restrict__ sorted,
                                   const int* __restrict__ bucketPtr,
                                   int* __restrict__ partialD, int N) {
    __shared__ int lhist[BSZ];
    int t = threadIdx.x;
    int bk = blockIdx.x >> 2, sp = blockIdx.x & 3;
    for (int l = t; l < BSZ; l += AGG_THREADS) lhist[l] = 0;
    __syncthreads();
    int beg = bucketPtr[bk], end = bucketPtr[bk + 1], len = end - beg;
    int s0 = beg + (int)(((long long)len * sp) >> 2);
    int s1 = beg + (int)(((long long)len * (sp + 1)) >> 2);
    for (int j = s0 + t; j < s1; j += AGG_THREADS)
        atomicAdd(&lhist[ntload_u(&sorted[j]) & (BSZ - 1)], 1);
    __syncthreads();
    size_t base = (size_t)sp * N;
    for (int l = t; l < BSZ; l += AGG_THREADS) {
        int i = (bk << SHIFT) + l;
        if (i < N) __builtin_nontemporal_store(lhist[l], &partialD[base + i]);
    }
}

// D2: deg = sum of partials -> degA; thp = packed 3x21-bit fixed point of
// x*rsqrt(deg+1), pre-biased: e_i = round(clamp(v_i)*2^12)+2^14 at bit 21*i.
__global__ void deg_xd_kernel(const int* __restrict__ partialD, const float* __restrict__ x,
                              int* __restrict__ degA, unsigned long long* __restrict__ thp, int N) {
    int i = blockIdx.x * blockDim.x + threadIdx.x;
    if (i >= N) return;
    int deg = ntload_i(&partialD[i]) + ntload_i(&partialD[(size_t)N + i]) +
              ntload_i(&partialD[2 * (size_t)N + i]) + ntload_i(&partialD[3 * (size_t)N + i]);
    degA[i] = deg;
    float di = rsqrtf((float)(deg + 1));
    float v0 = fminf(fmaxf(x[3 * i] * di, -CLV1), CLV1);
    float v1 = fminf(fmaxf(x[3 * i + 1] * di, -CLV1), CLV1);
    float v2 = fminf(fmaxf(x[3 * i + 2] * di, -CLV1), CLV1);
    unsigned e0 = (unsigned)(__float2int_rn(v0 * S1F) + B1);
    unsigned e1 = (unsigned)(__float2int_rn(v1 * S1F) + B1);
    unsigned e2 = (unsigned)(__float2int_rn(v2 * S1F) + B1);
    thp[i] = (unsigned long long)e0 | ((unsigned long long)e1 << 21)
           | ((unsigned long long)e2 << 42);
}

// E1: split-K LDS accumulation of thp[src]: per edge ONE ds_add_u64
// (3 pre-packed, pre-biased 21-bit fields; carry-free by construction).
__global__ void agg1_partial_kernel(const unsigned int* __restrict__ sorted,
                                    const int* __restrict__ bucketPtr,
                                    const unsigned long long* __restrict__ thp,
                                    unsigned long long* __restrict__ partial1, int N) {
    __shared__ unsigned long long a01[BSZ];    // 16KB
    int t = threadIdx.x;
    int bk = blockIdx.x >> 2, sp = blockIdx.x & 3;
    for (int l = t; l < BSZ; l += AGG_THREADS) a01[l] = 0ULL;
    __syncthreads();
    int beg = bucketPtr[bk], end = bucketPtr[bk + 1], len = end - beg;
    int s0 = beg + (int)(((long long)len * sp) >> 2);
    int s1 = beg + (int)(((long long)len * (sp + 1)) >> 2);
    for (int j = s0 + t; j < s1; j += AGG_THREADS) {
        unsigned int rec = ntload_u(&sorted[j]);
        int s = rec >> SHIFT;
        int ld = rec & (BSZ - 1);
        atomicAdd(&a01[ld], thp[s]);           // ONE ds_add_u64 per edge
    }
    __syncthreads();
    size_t base = (size_t)sp * N;
    for (int l = t; l < BSZ; l += AGG_THREADS) {
        int i = (bk << SHIFT) + l;
        if (i < N) ntstore_u64(a01[l], &partial1[base + i]);
    }
}

// E2: decode 4 partials (field-wise; exact int unbias via deg) + fp32 self;
// fused W1 + ReLU + W2 -> z (float2 table, 4 MB).
__global__ void z_epilogue_kernel(const unsigned long long* __restrict__ partial1,
                                  const float* __restrict__ x, const int* __restrict__ degA,
                                  const float* __restrict__ W1, const float* __restrict__ b1,
                                  const float* __restrict__ W2, float2* __restrict__ z, int N) {
    int i = blockIdx.x * blockDim.x + threadIdx.x;
    if (i >= N) return;
    unsigned long long q = ntload_u64(&partial1[i]) + ntload_u64(&partial1[(size_t)N + i]) +
                           ntload_u64(&partial1[2 * (size_t)N + i]) +
                           ntload_u64(&partial1[3 * (size_t)N + i]);
    int deg = ntload_i(&degA[i]);
    float di = rsqrtf((float)(deg + 1));
    int bias = deg * B1;                       // <= 45*2^14 < 2^20, exact
    int f0 = (int)(unsigned)(q & FMASK);
    int f1 = (int)(unsigned)((q >> 21) & FMASK);
    int f2 = (int)(unsigned)(q >> 42);
    float x0 = x[3 * i], x1 = x[3 * i + 1], x2 = x[3 * i + 2];
    float s0 = ((float)(f0 - bias) * IS1F + x0 * di) * di;
    float s1 = ((float)(f1 - bias) * IS1F + x1 * di) * di;
    float s2 = ((float)(f2 - bias) * IS1F + x2 * di) * di;
    float m0 = 0.f, m1 = 0.f;
#pragma unroll
    for (int k = 0; k < 8; ++k) {
        float h = fmaxf(s0 * W1[k] + s1 * W1[8 + k] + s2 * W1[16 + k] + b1[k], 0.0f);
        m0 += h * W2[2 * k];
        m1 += h * W2[2 * k + 1];
    }
    z[i] = make_float2(m0 * di, m1 * di);
}

// F1: split-K fixed-point LDS accumulation of z[src]: ONE ds_add_u64 per edge
// (2x32-bit biased fields, carry-free).
__global__ void agg2_partial_kernel(const unsigned int* __restrict__ sorted,
                                    const int* __restrict__ bucketPtr,
                                    const float2* __restrict__ z,
                                    unsigned long long* __restrict__ p2, int N) {
    __shared__ unsigned long long a01[BSZ];    // 16KB
    int t = threadIdx.x;
    int bk = blockIdx.x >> 2, sp = blockIdx.x & 3;
    for (int l = t; l < BSZ; l += AGG_THREADS) a01[l] = 0ULL;
    __syncthreads();
    int beg = bucketPtr[bk], end = bucketPtr[bk + 1], len = end - beg;
    int s0 = beg + (int)(((long long)len * sp) >> 2);
    int s1 = beg + (int)(((long long)len * (sp + 1)) >> 2);
    for (int j = s0 + t; j < s1; j += AGG_THREADS) {
        unsigned int rec = ntload_u(&sorted[j]);
        int s = rec >> SHIFT;
        int ld = rec & (BSZ - 1);
        float2 zv = z[s];
        float z0 = fminf(fmaxf(zv.x, -CLV2), CLV2);
        float z1 = fminf(fmaxf(zv.y, -CLV2), CLV2);
        unsigned e0 = (unsigned)(__float2int_rn(z0 * S2F) + BI2);
        unsigned e1 = (unsigned)(__float2int_rn(z1 * S2F) + BI2);
        atomicAdd(&a01[ld], ((unsigned long long)e1 << 32) | e0);   // ds_add_u64
    }
    __syncthreads();
    size_t base = (size_t)sp * N;
    for (int l = t; l < BSZ; l += AGG_THREADS) {
        int i = (bk << SHIFT) + l;
        if (i < N) ntstore_u64(a01[l], &p2[base + i]);
    }
}

// F2: decode 4 partials + self -> out.
__global__ void out_epilogue_kernel(const unsigned long long* __restrict__ p2,
                                    const float2* __restrict__ z, const int* __restrict__ degA,
                                    const float* __restrict__ b2, float* __restrict__ out, int N) {
    int i = blockIdx.x * blockDim.x + threadIdx.x;
    if (i >= N) return;
    unsigned long long q = ntload_u64(&p2[i]) + ntload_u64(&p2[(size_t)N + i]) +
                           ntload_u64(&p2[2 * (size_t)N + i]) + ntload_u64(&p2[3 * (size_t)N + i]);
    int deg = ntload_i(&degA[i]);
    float di = rsqrtf((float)(deg + 1));
    int bias = deg * BI2;
    float sum0 = (float)((int)(unsigned)q - bias) * IS2F;
    float sum1 = (float)((int)(unsigned)(q >> 32) - bias) * IS2F;
    const float2 zs = z[i];
    out[(size_t)i * 2]     = di * (sum0 + zs.x) + b2[0];
    out[(size_t)i * 2 + 1] = di * (sum1 + zs.y) + b2[1];
}

extern "C" void kernel_launch(void* const* d_in, const int* in_sizes, int n_in,
                              void* d_out, int out_size, void* d_ws, size_t ws_size,
                              hipStream_t stream) {
    const float* x  = (const float*)d_in[0];
    const int*   ei = (const int*)d_in[1];   // [2, E] flat: src row, dst row
    const float* W1 = (const float*)d_in[2];
    const float* b1 = (const float*)d_in[3];
    const float* W2 = (const float*)d_in[4];
    const float* b2 = (const float*)d_in[5];
    float* out = (float*)d_out;

    const int N = in_sizes[0] / 3;
    const int E = in_sizes[1] / 2;
    const int NBK = (N + BSZ - 1) / BSZ;       // 245 buckets
    const int NBA = (E + CH - 1) / CH;         // 245 blocks in A/C

    // Workspace. `scratch` (32 MB) reused sequentially: partialD (D1->D2),
    // then partial1 (E1->E2), then p2 (F1->F2). All bytes written before read.
    char* ws = (char*)d_ws;
    size_t off = 0;
    auto alloc = [&](size_t bytes) { char* p = ws + off; off = (off + bytes + 15) & ~(size_t)15; return p; };
    int* histM           = (int*)alloc((size_t)NBK * NBA * 4);
    int* totals          = (int*)alloc((size_t)NBK * 4);
    int* bucketPtr       = (int*)alloc(((size_t)NBK + 1) * 4);
    char* scratch        = alloc((size_t)SPLIT * N * 16);
    int* degA            = (int*)alloc((size_t)N * 4);
    float2* z            = (float2*)alloc((size_t)N * 8);
    unsigned long long* thp = (unsigned long long*)alloc((size_t)N * 8);
    unsigned int* sorted = (unsigned int*)alloc((size_t)E * 4);
    unsigned short* rank16 = (unsigned short*)alloc((size_t)E * 2);
    int4* subPre         = (int4*)alloc((size_t)NBA * NBK * 16);
    (void)ws_size;

    int* partialD             = (int*)scratch;                 // SPLIT*N*4
    unsigned long long* partial1 = (unsigned long long*)scratch;  // SPLIT*N*8
    unsigned long long* p2    = (unsigned long long*)scratch;  // SPLIT*N*8

    const int nb = (N + 255) / 256;

    bucket_count_kernel<<<NBA, AC_THREADS, 0, stream>>>(ei + E, histM, rank16, subPre, E, NBA, NBK);
    colscan_kernel<<<NBK, 256, 0, stream>>>(histM, totals, NBA);
    bucketscan_kernel<<<1, 256, 0, stream>>>(totals, bucketPtr, NBK, E);
    bucket_scatter_kernel<<<NBA, AC_THREADS, 0, stream>>>(ei, histM, bucketPtr, rank16, subPre,
                                                          sorted, E, NBA, NBK);
    deg_partial_kernel<<<NBK * SPLIT, AGG_THREADS, 0, stream>>>(sorted, bucketPtr, partialD, N);
    deg_xd_kernel<<<nb, 256, 0, stream>>>(partialD, x, degA, thp, N);
    agg1_partial_kernel<<<NBK * SPLIT, AGG_THREADS, 0, stream>>>(sorted, bucketPtr, thp, partial1, N);
    z_epilogue_kernel<<<nb, 256, 0, stream>>>(partial1, x, degA, W1, b1, W2, z, N);
    agg2_partial_kernel<<<NBK * SPLIT, AGG_THREADS, 0, stream>>>(sorted, bucketPtr, z, p2, N);
    out_epilogue_kernel<<<nb, 256, 0, stream>>>(p2, z, degA, b2, out, N);
}

// Round 10
// 350.499 us; speedup vs baseline: 1.1895x; 1.1895x over previous
//
#include <hip/hip_runtime.h>

// 2-layer GCN via bucketed counting sort + split-K LDS aggregation.
// R23 = R21 (best: 337us) with ONE change: CH 32768 -> 16384 (NBA 245->490)
// in the count/scatter passes, raising their occupancy 7.7 -> 15.3 waves/CU.
// R22 lesson (reverted): the scatter's cursor atomic is LOAD-BEARING for
// store coalescing -- rank-precomputed positions decorrelate write order
// from execution order -> 7x write amplification (232MB, 147us). Keep the
// atomic cursor.
// Model (confirmed R20/R21): every edge-pass pays ~3.4 cy per LDS RMW
// instruction-lane per CU (width/flavor/address/occupancy-invariant floor
// ~46us/pass). Scatter's excess over floor (72-46 = ~2cy/edge of ei-load +
// store ISSUE) is the one component that should scale with occupancy:
// at 1.9 waves/SIMD the non-atomic instructions can't overlap the atomic
// pipe. Prediction: scatter 72 -> 55-62, count ~44-48, total 337 -> 316-326.
// Falsifier: scatter >= 68 at 15 waves/CU => pass cost intrinsic => fuse
// count+scatter (slab-local) or declare ~315 structural roofline.
// Edge record u32: rec = (src<<11) | (dst&2047)  (src < 2^19).
//
// Pipeline (zero global atomics; LDS atomics only):
//   A  bucket_count   : per-block LDS hist (4-way sub-hist) -> histM[bk][blkA]
//   B1 colscan        : exclusive scan of histM rows + totals
//   B2 bucketscan     : exclusive scan of totals -> bucketPtr
//   C  bucket_scatter : place recs via bucketPtr + colPrefix + LDS cursor
//   D1 deg_partial    : split-K LDS hist -> partialD[sp][node]
//   D2 deg_xd         : deg -> degA; thp = packed 3x21b fixed point
//   E1 agg1_partial   : split-K LDS accum, ONE ds_add_u64 per edge
//   E2 z_epilogue     : decode partials + fp32 self; W1+ReLU+W2 -> z
//   F1 agg2_partial   : split-K LDS u64 fixed-point accum of z[src]
//   F2 out_epilogue   : decode partials + self -> out

#define SHIFT 11
#define BSZ   2048             // nodes per bucket
#define CH    16384            // edges per block in passes A/C (was 32768)
#define AC_THREADS 512
#define NBK_MAX 256
#define AGG_THREADS 512
#define SPLIT 4                // sub-blocks per bucket in D1/E1/F1

// layer-1 packed encoding: 3 fields x 21 bits
#define S1F  4096.0f           // 2^12
#define IS1F (1.0f/4096.0f)
#define B1   16384             // 2^14 bias per term
#define CLV1 3.999f
#define FMASK 0x1FFFFFu

// layer-2 encoding: 2 fields x 32 bits
#define S2F  131072.0f         // 2^17
#define IS2F (1.0f/131072.0f)
#define BI2  (1<<22)
#define CLV2 15.0f

typedef float vfloat4 __attribute__((ext_vector_type(4)));
typedef unsigned int vuint4 __attribute__((ext_vector_type(4)));

union H4 { uint2 u; _Float16 h[4]; };

__device__ __forceinline__ int ntload_i(const int* p) { return __builtin_nontemporal_load(p); }
__device__ __forceinline__ unsigned int ntload_u(const unsigned int* p) { return __builtin_nontemporal_load(p); }
__device__ __forceinline__ unsigned long long ntload_u64(const unsigned long long* p) {
    return __builtin_nontemporal_load(p);
}
__device__ __forceinline__ void ntstore_u64(unsigned long long v, unsigned long long* p) {
    __builtin_nontemporal_store(v, p);
}

__global__ void bucket_count_kernel(const int* __restrict__ dst, int* __restrict__ histM,
                                    int E, int NBA, int NBK) {
    __shared__ int lhist[4 * NBK_MAX];
    int t = threadIdx.x;
    for (int b = t; b < 4 * NBK; b += AC_THREADS) lhist[b] = 0;
    __syncthreads();
    int sub = t & 3;
    int base = blockIdx.x * CH;
#pragma unroll 8
    for (int k = 0; k < CH / AC_THREADS; ++k) {
        int e = base + t + k * AC_THREADS;
        if (e < E) atomicAdd(&lhist[((ntload_i(&dst[e]) >> SHIFT) << 2) | sub], 1);
    }
    __syncthreads();
    for (int b = t; b < NBK; b += AC_THREADS)
        histM[(size_t)b * NBA + blockIdx.x] =
            lhist[4 * b] + lhist[4 * b + 1] + lhist[4 * b + 2] + lhist[4 * b + 3];
}

// Exclusive scan of one bucket's row histM[bk][0..NBA-1] in place; totals[bk]=sum.
// Handles NBA up to 1024 (256 threads x 4).
__global__ void colscan_kernel(int* __restrict__ histM, int* __restrict__ totals,
                               int NBA) {
    __shared__ int sdata[256];
    int t = threadIdx.x;
    size_t base = (size_t)blockIdx.x * NBA;
    int v[4];
#pragma unroll
    for (int k = 0; k < 4; ++k) { int i = t * 4 + k; v[k] = (i < NBA) ? histM[base + i] : 0; }
    int s = v[0] + v[1] + v[2] + v[3];
    sdata[t] = s;
    __syncthreads();
    for (int off = 1; off < 256; off <<= 1) {
        int xv = (t >= off) ? sdata[t - off] : 0;
        __syncthreads();
        sdata[t] += xv;
        __syncthreads();
    }
    if (t == 255) totals[blockIdx.x] = sdata[255];
    int run = sdata[t] - s;
#pragma unroll
    for (int k = 0; k < 4; ++k) { int i = t * 4 + k; if (i < NBA) histM[base + i] = run; run += v[k]; }
}

// Exclusive scan of totals[NBK] -> bucketPtr; bucketPtr[NBK]=E.
__global__ void bucketscan_kernel(const int* __restrict__ totals, int* __restrict__ bucketPtr,
                                  int NBK, int E) {
    __shared__ int sdata[256];
    int t = threadIdx.x;
    int v[4];
#pragma unroll
    for (int k = 0; k < 4; ++k) { int i = t * 4 + k; v[k] = (i < NBK) ? totals[i] : 0; }
    int s = v[0] + v[1] + v[2] + v[3];
    sdata[t] = s;
    __syncthreads();
    for (int off = 1; off < 256; off <<= 1) {
        int xv = (t >= off) ? sdata[t - off] : 0;
        __syncthreads();
        sdata[t] += xv;
        __syncthreads();
    }
    int run = sdata[t] - s;
#pragma unroll
    for (int k = 0; k < 4; ++k) { int i = t * 4 + k; if (i < NBK) bucketPtr[i] = run; run += v[k]; }
    if (t == 255) bucketPtr[NBK] = E;
}

__global__ void bucket_scatter_kernel(const int* __restrict__ ei, const int* __restrict__ histM,
                                      const int* __restrict__ bucketPtr,
                                      unsigned int* __restrict__ sorted,
                                      int E, int NBA, int NBK) {
    __shared__ int cur[NBK_MAX];
    int t = threadIdx.x;
    for (int b = t; b < NBK; b += AC_THREADS)
        cur[b] = bucketPtr[b] + histM[(size_t)b * NBA + blockIdx.x];
    __syncthreads();
    int base = blockIdx.x * CH;
#pragma unroll 8
    for (int k = 0; k < CH / AC_THREADS; ++k) {
        int e = base + t + k * AC_THREADS;
        if (e < E) {
            int s = ntload_i(&ei[e]);
            int d = ntload_i(&ei[E + e]);
            int pos = atomicAdd(&cur[d >> SHIFT], 1);
            sorted[pos] = ((unsigned int)s << SHIFT) | (unsigned int)(d & (BSZ - 1));
        }
    }
}

// D1: split-K per-node degree histogram -> partialD[sp][node].
__global__ void deg_partial_kernel(const unsigned int* __restrict__ sorted,
                                   const int* __restrict__ bucketPtr,
                                   int* __restrict__ partialD, int N) {
    __shared__ int lhist[BSZ];
    int t = threadIdx.x;
    int bk = blockIdx.x >> 2, sp = blockIdx.x & 3;
    for (int l = t; l < BSZ; l += AGG_THREADS) lhist[l] = 0;
    __syncthreads();
    int beg = bucketPtr[bk], end = bucketPtr[bk + 1], len = end - beg;
    int s0 = beg + (int)(((long long)len * sp) >> 2);
    int s1 = beg + (int)(((long long)len * (sp + 1)) >> 2);
    for (int j = s0 + t; j < s1; j += AGG_THREADS)
        atomicAdd(&lhist[ntload_u(&sorted[j]) & (BSZ - 1)], 1);
    __syncthreads();
    size_t base = (size_t)sp * N;
    for (int l = t; l < BSZ; l += AGG_THREADS) {
        int i = (bk << SHIFT) + l;
        if (i < N) __builtin_nontemporal_store(lhist[l], &partialD[base + i]);
    }
}

// D2: deg = sum of partials -> degA; thp = packed 3x21-bit fixed point of
// x*rsqrt(deg+1), pre-biased: e_i = round(clamp(v_i)*2^12)+2^14 at bit 21*i.
__global__ void deg_xd_kernel(const int* __restrict__ partialD, const float* __restrict__ x,
                              int* __restrict__ degA, unsigned long long* __restrict__ thp, int N) {
    int i = blockIdx.x * blockDim.x + threadIdx.x;
    if (i >= N) return;
    int deg = ntload_i(&partialD[i]) + ntload_i(&partialD[(size_t)N + i]) +
              ntload_i(&partialD[2 * (size_t)N + i]) + ntload_i(&partialD[3 * (size_t)N + i]);
    degA[i] = deg;
    float di = rsqrtf((float)(deg + 1));
    float v0 = fminf(fmaxf(x[3 * i] * di, -CLV1), CLV1);
    float v1 = fminf(fmaxf(x[3 * i + 1] * di, -CLV1), CLV1);
    float v2 = fminf(fmaxf(x[3 * i + 2] * di, -CLV1), CLV1);
    unsigned e0 = (unsigned)(__float2int_rn(v0 * S1F) + B1);
    unsigned e1 = (unsigned)(__float2int_rn(v1 * S1F) + B1);
    unsigned e2 = (unsigned)(__float2int_rn(v2 * S1F) + B1);
    thp[i] = (unsigned long long)e0 | ((unsigned long long)e1 << 21)
           | ((unsigned long long)e2 << 42);
}

// E1: split-K LDS accumulation of thp[src]: per edge ONE ds_add_u64
// (3 pre-packed, pre-biased 21-bit fields; carry-free by construction).
__global__ void agg1_partial_kernel(const unsigned int* __restrict__ sorted,
                                    const int* __restrict__ bucketPtr,
                                    const unsigned long long* __restrict__ thp,
                                    unsigned long long* __restrict__ partial1, int N) {
    __shared__ unsigned long long a01[BSZ];    // 16KB
    int t = threadIdx.x;
    int bk = blockIdx.x >> 2, sp = blockIdx.x & 3;
    for (int l = t; l < BSZ; l += AGG_THREADS) a01[l] = 0ULL;
    __syncthreads();
    int beg = bucketPtr[bk], end = bucketPtr[bk + 1], len = end - beg;
    int s0 = beg + (int)(((long long)len * sp) >> 2);
    int s1 = beg + (int)(((long long)len * (sp + 1)) >> 2);
    for (int j = s0 + t; j < s1; j += AGG_THREADS) {
        unsigned int rec = ntload_u(&sorted[j]);
        int s = rec >> SHIFT;
        int ld = rec & (BSZ - 1);
        atomicAdd(&a01[ld], thp[s]);           // ONE ds_add_u64 per edge
    }
    __syncthreads();
    size_t base = (size_t)sp * N;
    for (int l = t; l < BSZ; l += AGG_THREADS) {
        int i = (bk << SHIFT) + l;
        if (i < N) ntstore_u64(a01[l], &partial1[base + i]);
    }
}

// E2: decode 4 partials (field-wise; exact int unbias via deg) + fp32 self;
// fused W1 + ReLU + W2 -> z (float2 table, 4 MB).
__global__ void z_epilogue_kernel(const unsigned long long* __restrict__ partial1,
                                  const float* __restrict__ x, const int* __restrict__ degA,
                                  const float* __restrict__ W1, const float* __restrict__ b1,
                                  const float* __restrict__ W2, float2* __restrict__ z, int N) {
    int i = blockIdx.x * blockDim.x + threadIdx.x;
    if (i >= N) return;
    unsigned long long q = ntload_u64(&partial1[i]) + ntload_u64(&partial1[(size_t)N + i]) +
                           ntload_u64(&partial1[2 * (size_t)N + i]) +
                           ntload_u64(&partial1[3 * (size_t)N + i]);
    int deg = ntload_i(&degA[i]);
    float di = rsqrtf((float)(deg + 1));
    int bias = deg * B1;                       // <= 45*2^14 < 2^20, exact
    int f0 = (int)(unsigned)(q & FMASK);
    int f1 = (int)(unsigned)((q >> 21) & FMASK);
    int f2 = (int)(unsigned)(q >> 42);
    float x0 = x[3 * i], x1 = x[3 * i + 1], x2 = x[3 * i + 2];
    float s0 = ((float)(f0 - bias) * IS1F + x0 * di) * di;
    float s1 = ((float)(f1 - bias) * IS1F + x1 * di) * di;
    float s2 = ((float)(f2 - bias) * IS1F + x2 * di) * di;
    float m0 = 0.f, m1 = 0.f;
#pragma unroll
    for (int k = 0; k < 8; ++k) {
        float h = fmaxf(s0 * W1[k] + s1 * W1[8 + k] + s2 * W1[16 + k] + b1[k], 0.0f);
        m0 += h * W2[2 * k];
        m1 += h * W2[2 * k + 1];
    }
    z[i] = make_float2(m0 * di, m1 * di);
}

// F1: split-K fixed-point LDS accumulation of z[src]: ONE ds_add_u64 per edge
// (2x32-bit biased fields, carry-free).
__global__ void agg2_partial_kernel(const unsigned int* __restrict__ sorted,
                                    const int* __restrict__ bucketPtr,
                                    const float2* __restrict__ z,
                                    unsigned long long* __restrict__ p2, int N) {
    __shared__ unsigned long long a01[BSZ];    // 16KB
    int t = threadIdx.x;
    int bk = blockIdx.x >> 2, sp = blockIdx.x & 3;
    for (int l = t; l < BSZ; l += AGG_THREADS) a01[l] = 0ULL;
    __syncthreads();
    int beg = bucketPtr[bk], end = bucketPtr[bk + 1], len = end - beg;
    int s0 = beg + (int)(((long long)len * sp) >> 2);
    int s1 = beg + (int)(((long long)len * (sp + 1)) >> 2);
    for (int j = s0 + t; j < s1; j += AGG_THREADS) {
        unsigned int rec = ntload_u(&sorted[j]);
        int s = rec >> SHIFT;
        int ld = rec & (BSZ - 1);
        float2 zv = z[s];
        float z0 = fminf(fmaxf(zv.x, -CLV2), CLV2);
        float z1 = fminf(fmaxf(zv.y, -CLV2), CLV2);
        unsigned e0 = (unsigned)(__float2int_rn(z0 * S2F) + BI2);
        unsigned e1 = (unsigned)(__float2int_rn(z1 * S2F) + BI2);
        atomicAdd(&a01[ld], ((unsigned long long)e1 << 32) | e0);   // ds_add_u64
    }
    __syncthreads();
    size_t base = (size_t)sp * N;
    for (int l = t; l < BSZ; l += AGG_THREADS) {
        int i = (bk << SHIFT) + l;
        if (i < N) ntstore_u64(a01[l], &p2[base + i]);
    }
}

// F2: decode 4 partials + self -> out.
__global__ void out_epilogue_kernel(const unsigned long long* __restrict__ p2,
                                    const float2* __restrict__ z, const int* __restrict__ degA,
                                    const float* __restrict__ b2, float* __restrict__ out, int N) {
    int i = blockIdx.x * blockDim.x + threadIdx.x;
    if (i >= N) return;
    unsigned long long q = ntload_u64(&p2[i]) + ntload_u64(&p2[(size_t)N + i]) +
                           ntload_u64(&p2[2 * (size_t)N + i]) + ntload_u64(&p2[3 * (size_t)N + i]);
    int deg = ntload_i(&degA[i]);
    float di = rsqrtf((float)(deg + 1));
    int bias = deg * BI2;
    float sum0 = (float)((int)(unsigned)q - bias) * IS2F;
    float sum1 = (float)((int)(unsigned)(q >> 32) - bias) * IS2F;
    const float2 zs = z[i];
    out[(size_t)i * 2]     = di * (sum0 + zs.x) + b2[0];
    out[(size_t)i * 2 + 1] = di * (sum1 + zs.y) + b2[1];
}

extern "C" void kernel_launch(void* const* d_in, const int* in_sizes, int n_in,
                              void* d_out, int out_size, void* d_ws, size_t ws_size,
                              hipStream_t stream) {
    const float* x  = (const float*)d_in[0];
    const int*   ei = (const int*)d_in[1];   // [2, E] flat: src row, dst row
    const float* W1 = (const float*)d_in[2];
    const float* b1 = (const float*)d_in[3];
    const float* W2 = (const float*)d_in[4];
    const float* b2 = (const float*)d_in[5];
    float* out = (float*)d_out;

    const int N = in_sizes[0] / 3;
    const int E = in_sizes[1] / 2;
    const int NBK = (N + BSZ - 1) / BSZ;       // 245 buckets
    const int NBA = (E + CH - 1) / CH;         // 489 blocks in A/C

    // Workspace. `scratch` (32 MB) reused sequentially: partialD (D1->D2),
    // then partial1 (E1->E2), then p2 (F1->F2). All bytes written before read.
    char* ws = (char*)d_ws;
    size_t off = 0;
    auto alloc = [&](size_t bytes) { char* p = ws + off; off = (off + bytes + 15) & ~(size_t)15; return p; };
    int* histM           = (int*)alloc((size_t)NBK * NBA * 4);
    int* totals          = (int*)alloc((size_t)NBK * 4);
    int* bucketPtr       = (int*)alloc(((size_t)NBK + 1) * 4);
    char* scratch        = alloc((size_t)SPLIT * N * 16);
    int* degA            = (int*)alloc((size_t)N * 4);
    float2* z            = (float2*)alloc((size_t)N * 8);
    unsigned long long* thp = (unsigned long long*)alloc((size_t)N * 8);
    unsigned int* sorted = (unsigned int*)alloc((size_t)E * 4);
    (void)ws_size;

    int* partialD             = (int*)scratch;                 // SPLIT*N*4
    unsigned long long* partial1 = (unsigned long long*)scratch;  // SPLIT*N*8
    unsigned long long* p2    = (unsigned long long*)scratch;  // SPLIT*N*8

    const int nb = (N + 255) / 256;

    bucket_count_kernel<<<NBA, AC_THREADS, 0, stream>>>(ei + E, histM, E, NBA, NBK);
    colscan_kernel<<<NBK, 256, 0, stream>>>(histM, totals, NBA);
    bucketscan_kernel<<<1, 256, 0, stream>>>(totals, bucketPtr, NBK, E);
    bucket_scatter_kernel<<<NBA, AC_THREADS, 0, stream>>>(ei, histM, bucketPtr, sorted, E, NBA, NBK);
    deg_partial_kernel<<<NBK * SPLIT, AGG_THREADS, 0, stream>>>(sorted, bucketPtr, partialD, N);
    deg_xd_kernel<<<nb, 256, 0, stream>>>(partialD, x, degA, thp, N);
    agg1_partial_kernel<<<NBK * SPLIT, AGG_THREADS, 0, stream>>>(sorted, bucketPtr, thp, partial1, N);
    z_epilogue_kernel<<<nb, 256, 0, stream>>>(partial1, x, degA, W1, b1, W2, z, N);
    agg2_partial_kernel<<<NBK * SPLIT, AGG_THREADS, 0, stream>>>(sorted, bucketPtr, z, p2, N);
    out_epilogue_kernel<<<nb, 256, 0, stream>>>(p2, z, degA, b2, out, N);
}

// Round 11
// 323.720 us; speedup vs baseline: 1.2878x; 1.0827x over previous
//
#include <hip/hip_runtime.h>

// 2-layer GCN via bucketed counting sort + split-K LDS aggregation.
// R24 = R21 (best: 337us; CH=32768 restored) with ONE change:
// AC_THREADS 512 -> 1024 in count/scatter (16 waves/CU, NBA=245 unchanged).
// R23 lesson: write locality is set by run length = CH/NBK; halving CH
// halved runs -> write amp 1.18x -> 2.8x (91MB), scatter 72->95us. The
// occupancy lever must be threads/block, which keeps runs at 133 entries.
// Model (confirmed R20/R21): each edge-pass pays ~3.4cy/edge/CU of LDS-RMW
// floor (~46us/pass, occupancy-invariant); scatter's ~26us excess is
// load/store ISSUE that can't overlap the DS pipe at 2 waves/SIMD.
// Prediction: scatter 72 -> 56-64 (WRITE back to ~38MB), count ~46,
// total -> 318-328. Falsifier: scatter >= 68 at 16 waves/CU => excess is
// intrinsic write-drain => fuse count+scatter w/ global-cursor reservation;
// practical roofline ~ 5x46 + structural ~ 310.
// Edge record u32: rec = (src<<11) | (dst&2047)  (src < 2^19).
//
// Pipeline (zero global atomics; LDS atomics only):
//   A  bucket_count   : per-block LDS hist (4-way sub-hist) -> histM[bk][blkA]
//   B1 colscan        : exclusive scan of histM rows + totals
//   B2 bucketscan     : exclusive scan of totals -> bucketPtr
//   C  bucket_scatter : place recs via bucketPtr + colPrefix + LDS cursor
//   D1 deg_partial    : split-K LDS hist -> partialD[sp][node]
//   D2 deg_xd         : deg -> degA; thp = packed 3x21b fixed point
//   E1 agg1_partial   : split-K LDS accum, ONE ds_add_u64 per edge
//   E2 z_epilogue     : decode partials + fp32 self; W1+ReLU+W2 -> z
//   F1 agg2_partial   : split-K LDS u64 fixed-point accum of z[src]
//   F2 out_epilogue   : decode partials + self -> out

#define SHIFT 11
#define BSZ   2048             // nodes per bucket
#define CH    32768            // edges per block in passes A/C
#define AC_THREADS 1024        // was 512: 16 waves/CU at NBA=245
#define NBK_MAX 256
#define AGG_THREADS 512
#define SPLIT 4                // sub-blocks per bucket in D1/E1/F1

// layer-1 packed encoding: 3 fields x 21 bits
#define S1F  4096.0f           // 2^12
#define IS1F (1.0f/4096.0f)
#define B1   16384             // 2^14 bias per term
#define CLV1 3.999f
#define FMASK 0x1FFFFFu

// layer-2 encoding: 2 fields x 32 bits
#define S2F  131072.0f         // 2^17
#define IS2F (1.0f/131072.0f)
#define BI2  (1<<22)
#define CLV2 15.0f

typedef float vfloat4 __attribute__((ext_vector_type(4)));
typedef unsigned int vuint4 __attribute__((ext_vector_type(4)));

union H4 { uint2 u; _Float16 h[4]; };

__device__ __forceinline__ int ntload_i(const int* p) { return __builtin_nontemporal_load(p); }
__device__ __forceinline__ unsigned int ntload_u(const unsigned int* p) { return __builtin_nontemporal_load(p); }
__device__ __forceinline__ unsigned long long ntload_u64(const unsigned long long* p) {
    return __builtin_nontemporal_load(p);
}
__device__ __forceinline__ void ntstore_u64(unsigned long long v, unsigned long long* p) {
    __builtin_nontemporal_store(v, p);
}

__global__ __launch_bounds__(AC_THREADS) void bucket_count_kernel(
        const int* __restrict__ dst, int* __restrict__ histM,
        int E, int NBA, int NBK) {
    __shared__ int lhist[4 * NBK_MAX];
    int t = threadIdx.x;
    for (int b = t; b < 4 * NBK; b += AC_THREADS) lhist[b] = 0;
    __syncthreads();
    int sub = t & 3;
    int base = blockIdx.x * CH;
#pragma unroll 8
    for (int k = 0; k < CH / AC_THREADS; ++k) {
        int e = base + t + k * AC_THREADS;
        if (e < E) atomicAdd(&lhist[((ntload_i(&dst[e]) >> SHIFT) << 2) | sub], 1);
    }
    __syncthreads();
    for (int b = t; b < NBK; b += AC_THREADS)
        histM[(size_t)b * NBA + blockIdx.x] =
            lhist[4 * b] + lhist[4 * b + 1] + lhist[4 * b + 2] + lhist[4 * b + 3];
}

// Exclusive scan of one bucket's row histM[bk][0..NBA-1] in place; totals[bk]=sum.
__global__ void colscan_kernel(int* __restrict__ histM, int* __restrict__ totals,
                               int NBA) {
    __shared__ int sdata[256];
    int t = threadIdx.x;
    size_t base = (size_t)blockIdx.x * NBA;
    int v[4];
#pragma unroll
    for (int k = 0; k < 4; ++k) { int i = t * 4 + k; v[k] = (i < NBA) ? histM[base + i] : 0; }
    int s = v[0] + v[1] + v[2] + v[3];
    sdata[t] = s;
    __syncthreads();
    for (int off = 1; off < 256; off <<= 1) {
        int xv = (t >= off) ? sdata[t - off] : 0;
        __syncthreads();
        sdata[t] += xv;
        __syncthreads();
    }
    if (t == 255) totals[blockIdx.x] = sdata[255];
    int run = sdata[t] - s;
#pragma unroll
    for (int k = 0; k < 4; ++k) { int i = t * 4 + k; if (i < NBA) histM[base + i] = run; run += v[k]; }
}

// Exclusive scan of totals[NBK] -> bucketPtr; bucketPtr[NBK]=E.
__global__ void bucketscan_kernel(const int* __restrict__ totals, int* __restrict__ bucketPtr,
                                  int NBK, int E) {
    __shared__ int sdata[256];
    int t = threadIdx.x;
    int v[4];
#pragma unroll
    for (int k = 0; k < 4; ++k) { int i = t * 4 + k; v[k] = (i < NBK) ? totals[i] : 0; }
    int s = v[0] + v[1] + v[2] + v[3];
    sdata[t] = s;
    __syncthreads();
    for (int off = 1; off < 256; off <<= 1) {
        int xv = (t >= off) ? sdata[t - off] : 0;
        __syncthreads();
        sdata[t] += xv;
        __syncthreads();
    }
    int run = sdata[t] - s;
#pragma unroll
    for (int k = 0; k < 4; ++k) { int i = t * 4 + k; if (i < NBK) bucketPtr[i] = run; run += v[k]; }
    if (t == 255) bucketPtr[NBK] = E;
}

__global__ __launch_bounds__(AC_THREADS) void bucket_scatter_kernel(
        const int* __restrict__ ei, const int* __restrict__ histM,
        const int* __restrict__ bucketPtr,
        unsigned int* __restrict__ sorted,
        int E, int NBA, int NBK) {
    __shared__ int cur[NBK_MAX];
    int t = threadIdx.x;
    for (int b = t; b < NBK; b += AC_THREADS)
        cur[b] = bucketPtr[b] + histM[(size_t)b * NBA + blockIdx.x];
    __syncthreads();
    int base = blockIdx.x * CH;
#pragma unroll 8
    for (int k = 0; k < CH / AC_THREADS; ++k) {
        int e = base + t + k * AC_THREADS;
        if (e < E) {
            int s = ntload_i(&ei[e]);
            int d = ntload_i(&ei[E + e]);
            int pos = atomicAdd(&cur[d >> SHIFT], 1);
            sorted[pos] = ((unsigned int)s << SHIFT) | (unsigned int)(d & (BSZ - 1));
        }
    }
}

// D1: split-K per-node degree histogram -> partialD[sp][node].
__global__ void deg_partial_kernel(const unsigned int* __restrict__ sorted,
                                   const int* __restrict__ bucketPtr,
                                   int* __restrict__ partialD, int N) {
    __shared__ int lhist[BSZ];
    int t = threadIdx.x;
    int bk = blockIdx.x >> 2, sp = blockIdx.x & 3;
    for (int l = t; l < BSZ; l += AGG_THREADS) lhist[l] = 0;
    __syncthreads();
    int beg = bucketPtr[bk], end = bucketPtr[bk + 1], len = end - beg;
    int s0 = beg + (int)(((long long)len * sp) >> 2);
    int s1 = beg + (int)(((long long)len * (sp + 1)) >> 2);
    for (int j = s0 + t; j < s1; j += AGG_THREADS)
        atomicAdd(&lhist[ntload_u(&sorted[j]) & (BSZ - 1)], 1);
    __syncthreads();
    size_t base = (size_t)sp * N;
    for (int l = t; l < BSZ; l += AGG_THREADS) {
        int i = (bk << SHIFT) + l;
        if (i < N) __builtin_nontemporal_store(lhist[l], &partialD[base + i]);
    }
}

// D2: deg = sum of partials -> degA; thp = packed 3x21-bit fixed point of
// x*rsqrt(deg+1), pre-biased: e_i = round(clamp(v_i)*2^12)+2^14 at bit 21*i.
__global__ void deg_xd_kernel(const int* __restrict__ partialD, const float* __restrict__ x,
                              int* __restrict__ degA, unsigned long long* __restrict__ thp, int N) {
    int i = blockIdx.x * blockDim.x + threadIdx.x;
    if (i >= N) return;
    int deg = ntload_i(&partialD[i]) + ntload_i(&partialD[(size_t)N + i]) +
              ntload_i(&partialD[2 * (size_t)N + i]) + ntload_i(&partialD[3 * (size_t)N + i]);
    degA[i] = deg;
    float di = rsqrtf((float)(deg + 1));
    float v0 = fminf(fmaxf(x[3 * i] * di, -CLV1), CLV1);
    float v1 = fminf(fmaxf(x[3 * i + 1] * di, -CLV1), CLV1);
    float v2 = fminf(fmaxf(x[3 * i + 2] * di, -CLV1), CLV1);
    unsigned e0 = (unsigned)(__float2int_rn(v0 * S1F) + B1);
    unsigned e1 = (unsigned)(__float2int_rn(v1 * S1F) + B1);
    unsigned e2 = (unsigned)(__float2int_rn(v2 * S1F) + B1);
    thp[i] = (unsigned long long)e0 | ((unsigned long long)e1 << 21)
           | ((unsigned long long)e2 << 42);
}

// E1: split-K LDS accumulation of thp[src]: per edge ONE ds_add_u64
// (3 pre-packed, pre-biased 21-bit fields; carry-free by construction).
__global__ void agg1_partial_kernel(const unsigned int* __restrict__ sorted,
                                    const int* __restrict__ bucketPtr,
                                    const unsigned long long* __restrict__ thp,
                                    unsigned long long* __restrict__ partial1, int N) {
    __shared__ unsigned long long a01[BSZ];    // 16KB
    int t = threadIdx.x;
    int bk = blockIdx.x >> 2, sp = blockIdx.x & 3;
    for (int l = t; l < BSZ; l += AGG_THREADS) a01[l] = 0ULL;
    __syncthreads();
    int beg = bucketPtr[bk], end = bucketPtr[bk + 1], len = end - beg;
    int s0 = beg + (int)(((long long)len * sp) >> 2);
    int s1 = beg + (int)(((long long)len * (sp + 1)) >> 2);
    for (int j = s0 + t; j < s1; j += AGG_THREADS) {
        unsigned int rec = ntload_u(&sorted[j]);
        int s = rec >> SHIFT;
        int ld = rec & (BSZ - 1);
        atomicAdd(&a01[ld], thp[s]);           // ONE ds_add_u64 per edge
    }
    __syncthreads();
    size_t base = (size_t)sp * N;
    for (int l = t; l < BSZ; l += AGG_THREADS) {
        int i = (bk << SHIFT) + l;
        if (i < N) ntstore_u64(a01[l], &partial1[base + i]);
    }
}

// E2: decode 4 partials (field-wise; exact int unbias via deg) + fp32 self;
// fused W1 + ReLU + W2 -> z (float2 table, 4 MB).
__global__ void z_epilogue_kernel(const unsigned long long* __restrict__ partial1,
                                  const float* __restrict__ x, const int* __restrict__ degA,
                                  const float* __restrict__ W1, const float* __restrict__ b1,
                                  const float* __restrict__ W2, float2* __restrict__ z, int N) {
    int i = blockIdx.x * blockDim.x + threadIdx.x;
    if (i >= N) return;
    unsigned long long q = ntload_u64(&partial1[i]) + ntload_u64(&partial1[(size_t)N + i]) +
                           ntload_u64(&partial1[2 * (size_t)N + i]) +
                           ntload_u64(&partial1[3 * (size_t)N + i]);
    int deg = ntload_i(&degA[i]);
    float di = rsqrtf((float)(deg + 1));
    int bias = deg * B1;                       // <= 45*2^14 < 2^20, exact
    int f0 = (int)(unsigned)(q & FMASK);
    int f1 = (int)(unsigned)((q >> 21) & FMASK);
    int f2 = (int)(unsigned)(q >> 42);
    float x0 = x[3 * i], x1 = x[3 * i + 1], x2 = x[3 * i + 2];
    float s0 = ((float)(f0 - bias) * IS1F + x0 * di) * di;
    float s1 = ((float)(f1 - bias) * IS1F + x1 * di) * di;
    float s2 = ((float)(f2 - bias) * IS1F + x2 * di) * di;
    float m0 = 0.f, m1 = 0.f;
#pragma unroll
    for (int k = 0; k < 8; ++k) {
        float h = fmaxf(s0 * W1[k] + s1 * W1[8 + k] + s2 * W1[16 + k] + b1[k], 0.0f);
        m0 += h * W2[2 * k];
        m1 += h * W2[2 * k + 1];
    }
    z[i] = make_float2(m0 * di, m1 * di);
}

// F1: split-K fixed-point LDS accumulation of z[src]: ONE ds_add_u64 per edge
// (2x32-bit biased fields, carry-free).
__global__ void agg2_partial_kernel(const unsigned int* __restrict__ sorted,
                                    const int* __restrict__ bucketPtr,
                                    const float2* __restrict__ z,
                                    unsigned long long* __restrict__ p2, int N) {
    __shared__ unsigned long long a01[BSZ];    // 16KB
    int t = threadIdx.x;
    int bk = blockIdx.x >> 2, sp = blockIdx.x & 3;
    for (int l = t; l < BSZ; l += AGG_THREADS) a01[l] = 0ULL;
    __syncthreads();
    int beg = bucketPtr[bk], end = bucketPtr[bk + 1], len = end - beg;
    int s0 = beg + (int)(((long long)len * sp) >> 2);
    int s1 = beg + (int)(((long long)len * (sp + 1)) >> 2);
    for (int j = s0 + t; j < s1; j += AGG_THREADS) {
        unsigned int rec = ntload_u(&sorted[j]);
        int s = rec >> SHIFT;
        int ld = rec & (BSZ - 1);
        float2 zv = z[s];
        float z0 = fminf(fmaxf(zv.x, -CLV2), CLV2);
        float z1 = fminf(fmaxf(zv.y, -CLV2), CLV2);
        unsigned e0 = (unsigned)(__float2int_rn(z0 * S2F) + BI2);
        unsigned e1 = (unsigned)(__float2int_rn(z1 * S2F) + BI2);
        atomicAdd(&a01[ld], ((unsigned long long)e1 << 32) | e0);   // ds_add_u64
    }
    __syncthreads();
    size_t base = (size_t)sp * N;
    for (int l = t; l < BSZ; l += AGG_THREADS) {
        int i = (bk << SHIFT) + l;
        if (i < N) ntstore_u64(a01[l], &p2[base + i]);
    }
}

// F2: decode 4 partials + self -> out.
__global__ void out_epilogue_kernel(const unsigned long long* __restrict__ p2,
                                    const float2* __restrict__ z, const int* __restrict__ degA,
                                    const float* __restrict__ b2, float* __restrict__ out, int N) {
    int i = blockIdx.x * blockDim.x + threadIdx.x;
    if (i >= N) return;
    unsigned long long q = ntload_u64(&p2[i]) + ntload_u64(&p2[(size_t)N + i]) +
                           ntload_u64(&p2[2 * (size_t)N + i]) + ntload_u64(&p2[3 * (size_t)N + i]);
    int deg = ntload_i(&degA[i]);
    float di = rsqrtf((float)(deg + 1));
    int bias = deg * BI2;
    float sum0 = (float)((int)(unsigned)q - bias) * IS2F;
    float sum1 = (float)((int)(unsigned)(q >> 32) - bias) * IS2F;
    const float2 zs = z[i];
    out[(size_t)i * 2]     = di * (sum0 + zs.x) + b2[0];
    out[(size_t)i * 2 + 1] = di * (sum1 + zs.y) + b2[1];
}

extern "C" void kernel_launch(void* const* d_in, const int* in_sizes, int n_in,
                              void* d_out, int out_size, void* d_ws, size_t ws_size,
                              hipStream_t stream) {
    const float* x  = (const float*)d_in[0];
    const int*   ei = (const int*)d_in[1];   // [2, E] flat: src row, dst row
    const float* W1 = (const float*)d_in[2];
    const float* b1 = (const float*)d_in[3];
    const float* W2 = (const float*)d_in[4];
    const float* b2 = (const float*)d_in[5];
    float* out = (float*)d_out;

    const int N = in_sizes[0] / 3;
    const int E = in_sizes[1] / 2;
    const int NBK = (N + BSZ - 1) / BSZ;       // 245 buckets
    const int NBA = (E + CH - 1) / CH;         // 245 blocks in A/C

    // Workspace. `scratch` (32 MB) reused sequentially: partialD (D1->D2),
    // then partial1 (E1->E2), then p2 (F1->F2). All bytes written before read.
    char* ws = (char*)d_ws;
    size_t off = 0;
    auto alloc = [&](size_t bytes) { char* p = ws + off; off = (off + bytes + 15) & ~(size_t)15; return p; };
    int* histM           = (int*)alloc((size_t)NBK * NBA * 4);
    int* totals          = (int*)alloc((size_t)NBK * 4);
    int* bucketPtr       = (int*)alloc(((size_t)NBK + 1) * 4);
    char* scratch        = alloc((size_t)SPLIT * N * 16);
    int* degA            = (int*)alloc((size_t)N * 4);
    float2* z            = (float2*)alloc((size_t)N * 8);
    unsigned long long* thp = (unsigned long long*)alloc((size_t)N * 8);
    unsigned int* sorted = (unsigned int*)alloc((size_t)E * 4);
    (void)ws_size;

    int* partialD             = (int*)scratch;                 // SPLIT*N*4
    unsigned long long* partial1 = (unsigned long long*)scratch;  // SPLIT*N*8
    unsigned long long* p2    = (unsigned long long*)scratch;  // SPLIT*N*8

    const int nb = (N + 255) / 256;

    bucket_count_kernel<<<NBA, AC_THREADS, 0, stream>>>(ei + E, histM, E, NBA, NBK);
    colscan_kernel<<<NBK, 256, 0, stream>>>(histM, totals, NBA);
    bucketscan_kernel<<<1, 256, 0, stream>>>(totals, bucketPtr, NBK, E);
    bucket_scatter_kernel<<<NBA, AC_THREADS, 0, stream>>>(ei, histM, bucketPtr, sorted, E, NBA, NBK);
    deg_partial_kernel<<<NBK * SPLIT, AGG_THREADS, 0, stream>>>(sorted, bucketPtr, partialD, N);
    deg_xd_kernel<<<nb, 256, 0, stream>>>(partialD, x, degA, thp, N);
    agg1_partial_kernel<<<NBK * SPLIT, AGG_THREADS, 0, stream>>>(sorted, bucketPtr, thp, partial1, N);
    z_epilogue_kernel<<<nb, 256, 0, stream>>>(partial1, x, degA, W1, b1, W2, z, N);
    agg2_partial_kernel<<<NBK * SPLIT, AGG_THREADS, 0, stream>>>(sorted, bucketPtr, z, p2, N);
    out_epilogue_kernel<<<nb, 256, 0, stream>>>(p2, z, degA, b2, out, N);
}

// Round 12
// 317.631 us; speedup vs baseline: 1.3125x; 1.0192x over previous
//
#include <hip/hip_runtime.h>

// 2-layer GCN via bucketed counting sort + split-K LDS aggregation.
// R25 = R24 (best: 324us) with the occupancy lever applied to the remaining
// RMW passes + VALU/traffic trims:
//  1. AGG_THREADS 512->1024, SPLIT 4->2 in deg/agg1/agg2 (32 waves/CU vs 15;
//     R24 showed non-atomic issue only overlaps the DS pipe at high waves/CU).
//  2. agg2 gathers PRE-PACKED u64 zp (encoded once/node in z_epilogue),
//     removing per-edge clamp/convert VALU (mirrors agg1's thp design).
//  3. partial buffers halved (SPLIT=2); out_epilogue decodes self from zp.
// Model (R20/R21/R24-confirmed): each edge-pass pays ~3.4cy/edge/CU LDS-RMW
// floor (~46us, occupancy/width/flavor-invariant); scatter's ~24us excess is
// intrinsic (divergent-store issue); non-atomic overhead hides at high occ.
// 5 RMW passes x 46 + scatter excess + structural ~= 300-310 roofline.
// Prediction: deg ~40, agg1 ~45, agg2 ~42, total 324 -> 302-312.
// Falsifier: total >= 320 => agg passes already at atomic floor => declare
// structural roofline (segmented-reduction rewrite is the only path left,
// gather-wall risk unresolved per R16).
// Edge record u32: rec = (src<<11) | (dst&2047)  (src < 2^19).
//
// Pipeline (zero global atomics; LDS atomics only):
//   A  bucket_count   : per-block LDS hist (4-way sub-hist) -> histM[bk][blkA]
//   B1 colscan        : exclusive scan of histM rows + totals
//   B2 bucketscan     : exclusive scan of totals -> bucketPtr
//   C  bucket_scatter : place recs via bucketPtr + colPrefix + LDS cursor
//   D1 deg_partial    : split-K LDS hist -> partialD[sp][node]
//   D2 deg_xd         : deg -> degA; thp = packed 3x21b fixed point
//   E1 agg1_partial   : split-K LDS accum, ONE ds_add_u64 per edge
//   E2 z_epilogue     : decode partials + fp32 self; W1+ReLU+W2 -> zp (u64)
//   F1 agg2_partial   : split-K LDS u64 accum of pre-packed zp[src]
//   F2 out_epilogue   : decode partials + self -> out

#define SHIFT 11
#define BSZ   2048             // nodes per bucket
#define CH    32768            // edges per block in passes A/C
#define AC_THREADS 1024
#define NBK_MAX 256
#define AGG_THREADS 1024       // was 512
#define SPLIT 2                // was 4: 490 blocks x 16 waves = 32 waves/CU

// layer-1 packed encoding: 3 fields x 21 bits
#define S1F  4096.0f           // 2^12
#define IS1F (1.0f/4096.0f)
#define B1   16384             // 2^14 bias per term
#define CLV1 3.999f
#define FMASK 0x1FFFFFu

// layer-2 encoding: 2 fields x 32 bits
#define S2F  131072.0f         // 2^17
#define IS2F (1.0f/131072.0f)
#define BI2  (1<<22)
#define CLV2 15.0f

typedef float vfloat4 __attribute__((ext_vector_type(4)));
typedef unsigned int vuint4 __attribute__((ext_vector_type(4)));

union H4 { uint2 u; _Float16 h[4]; };

__device__ __forceinline__ int ntload_i(const int* p) { return __builtin_nontemporal_load(p); }
__device__ __forceinline__ unsigned int ntload_u(const unsigned int* p) { return __builtin_nontemporal_load(p); }
__device__ __forceinline__ unsigned long long ntload_u64(const unsigned long long* p) {
    return __builtin_nontemporal_load(p);
}
__device__ __forceinline__ void ntstore_u64(unsigned long long v, unsigned long long* p) {
    __builtin_nontemporal_store(v, p);
}

__global__ __launch_bounds__(AC_THREADS) void bucket_count_kernel(
        const int* __restrict__ dst, int* __restrict__ histM,
        int E, int NBA, int NBK) {
    __shared__ int lhist[4 * NBK_MAX];
    int t = threadIdx.x;
    for (int b = t; b < 4 * NBK; b += AC_THREADS) lhist[b] = 0;
    __syncthreads();
    int sub = t & 3;
    int base = blockIdx.x * CH;
#pragma unroll 8
    for (int k = 0; k < CH / AC_THREADS; ++k) {
        int e = base + t + k * AC_THREADS;
        if (e < E) atomicAdd(&lhist[((ntload_i(&dst[e]) >> SHIFT) << 2) | sub], 1);
    }
    __syncthreads();
    for (int b = t; b < NBK; b += AC_THREADS)
        histM[(size_t)b * NBA + blockIdx.x] =
            lhist[4 * b] + lhist[4 * b + 1] + lhist[4 * b + 2] + lhist[4 * b + 3];
}

// Exclusive scan of one bucket's row histM[bk][0..NBA-1] in place; totals[bk]=sum.
__global__ void colscan_kernel(int* __restrict__ histM, int* __restrict__ totals,
                               int NBA) {
    __shared__ int sdata[256];
    int t = threadIdx.x;
    size_t base = (size_t)blockIdx.x * NBA;
    int v[4];
#pragma unroll
    for (int k = 0; k < 4; ++k) { int i = t * 4 + k; v[k] = (i < NBA) ? histM[base + i] : 0; }
    int s = v[0] + v[1] + v[2] + v[3];
    sdata[t] = s;
    __syncthreads();
    for (int off = 1; off < 256; off <<= 1) {
        int xv = (t >= off) ? sdata[t - off] : 0;
        __syncthreads();
        sdata[t] += xv;
        __syncthreads();
    }
    if (t == 255) totals[blockIdx.x] = sdata[255];
    int run = sdata[t] - s;
#pragma unroll
    for (int k = 0; k < 4; ++k) { int i = t * 4 + k; if (i < NBA) histM[base + i] = run; run += v[k]; }
}

// Exclusive scan of totals[NBK] -> bucketPtr; bucketPtr[NBK]=E.
__global__ void bucketscan_kernel(const int* __restrict__ totals, int* __restrict__ bucketPtr,
                                  int NBK, int E) {
    __shared__ int sdata[256];
    int t = threadIdx.x;
    int v[4];
#pragma unroll
    for (int k = 0; k < 4; ++k) { int i = t * 4 + k; v[k] = (i < NBK) ? totals[i] : 0; }
    int s = v[0] + v[1] + v[2] + v[3];
    sdata[t] = s;
    __syncthreads();
    for (int off = 1; off < 256; off <<= 1) {
        int xv = (t >= off) ? sdata[t - off] : 0;
        __syncthreads();
        sdata[t] += xv;
        __syncthreads();
    }
    int run = sdata[t] - s;
#pragma unroll
    for (int k = 0; k < 4; ++k) { int i = t * 4 + k; if (i < NBK) bucketPtr[i] = run; run += v[k]; }
    if (t == 255) bucketPtr[NBK] = E;
}

__global__ __launch_bounds__(AC_THREADS) void bucket_scatter_kernel(
        const int* __restrict__ ei, const int* __restrict__ histM,
        const int* __restrict__ bucketPtr,
        unsigned int* __restrict__ sorted,
        int E, int NBA, int NBK) {
    __shared__ int cur[NBK_MAX];
    int t = threadIdx.x;
    for (int b = t; b < NBK; b += AC_THREADS)
        cur[b] = bucketPtr[b] + histM[(size_t)b * NBA + blockIdx.x];
    __syncthreads();
    int base = blockIdx.x * CH;
#pragma unroll 8
    for (int k = 0; k < CH / AC_THREADS; ++k) {
        int e = base + t + k * AC_THREADS;
        if (e < E) {
            int s = ntload_i(&ei[e]);
            int d = ntload_i(&ei[E + e]);
            int pos = atomicAdd(&cur[d >> SHIFT], 1);
            sorted[pos] = ((unsigned int)s << SHIFT) | (unsigned int)(d & (BSZ - 1));
        }
    }
}

// D1: split-K per-node degree histogram -> partialD[sp][node].
__global__ __launch_bounds__(AGG_THREADS) void deg_partial_kernel(
        const unsigned int* __restrict__ sorted,
        const int* __restrict__ bucketPtr,
        int* __restrict__ partialD, int N) {
    __shared__ int lhist[BSZ];
    int t = threadIdx.x;
    int bk = blockIdx.x >> 1, sp = blockIdx.x & 1;
    for (int l = t; l < BSZ; l += AGG_THREADS) lhist[l] = 0;
    __syncthreads();
    int beg = bucketPtr[bk], end = bucketPtr[bk + 1], len = end - beg;
    int s0 = beg + (int)(((long long)len * sp) >> 1);
    int s1 = beg + (int)(((long long)len * (sp + 1)) >> 1);
    for (int j = s0 + t; j < s1; j += AGG_THREADS)
        atomicAdd(&lhist[ntload_u(&sorted[j]) & (BSZ - 1)], 1);
    __syncthreads();
    size_t base = (size_t)sp * N;
    for (int l = t; l < BSZ; l += AGG_THREADS) {
        int i = (bk << SHIFT) + l;
        if (i < N) __builtin_nontemporal_store(lhist[l], &partialD[base + i]);
    }
}

// D2: deg = sum of partials -> degA; thp = packed 3x21-bit fixed point of
// x*rsqrt(deg+1), pre-biased: e_i = round(clamp(v_i)*2^12)+2^14 at bit 21*i.
__global__ void deg_xd_kernel(const int* __restrict__ partialD, const float* __restrict__ x,
                              int* __restrict__ degA, unsigned long long* __restrict__ thp, int N) {
    int i = blockIdx.x * blockDim.x + threadIdx.x;
    if (i >= N) return;
    int deg = ntload_i(&partialD[i]) + ntload_i(&partialD[(size_t)N + i]);
    degA[i] = deg;
    float di = rsqrtf((float)(deg + 1));
    float v0 = fminf(fmaxf(x[3 * i] * di, -CLV1), CLV1);
    float v1 = fminf(fmaxf(x[3 * i + 1] * di, -CLV1), CLV1);
    float v2 = fminf(fmaxf(x[3 * i + 2] * di, -CLV1), CLV1);
    unsigned e0 = (unsigned)(__float2int_rn(v0 * S1F) + B1);
    unsigned e1 = (unsigned)(__float2int_rn(v1 * S1F) + B1);
    unsigned e2 = (unsigned)(__float2int_rn(v2 * S1F) + B1);
    thp[i] = (unsigned long long)e0 | ((unsigned long long)e1 << 21)
           | ((unsigned long long)e2 << 42);
}

// E1: split-K LDS accumulation of thp[src]: per edge ONE ds_add_u64
// (3 pre-packed, pre-biased 21-bit fields; carry-free by construction).
__global__ __launch_bounds__(AGG_THREADS) void agg1_partial_kernel(
        const unsigned int* __restrict__ sorted,
        const int* __restrict__ bucketPtr,
        const unsigned long long* __restrict__ thp,
        unsigned long long* __restrict__ partial1, int N) {
    __shared__ unsigned long long a01[BSZ];    // 16KB
    int t = threadIdx.x;
    int bk = blockIdx.x >> 1, sp = blockIdx.x & 1;
    for (int l = t; l < BSZ; l += AGG_THREADS) a01[l] = 0ULL;
    __syncthreads();
    int beg = bucketPtr[bk], end = bucketPtr[bk + 1], len = end - beg;
    int s0 = beg + (int)(((long long)len * sp) >> 1);
    int s1 = beg + (int)(((long long)len * (sp + 1)) >> 1);
    for (int j = s0 + t; j < s1; j += AGG_THREADS) {
        unsigned int rec = ntload_u(&sorted[j]);
        int s = rec >> SHIFT;
        int ld = rec & (BSZ - 1);
        atomicAdd(&a01[ld], thp[s]);           // ONE ds_add_u64 per edge
    }
    __syncthreads();
    size_t base = (size_t)sp * N;
    for (int l = t; l < BSZ; l += AGG_THREADS) {
        int i = (bk << SHIFT) + l;
        if (i < N) ntstore_u64(a01[l], &partial1[base + i]);
    }
}

// E2: decode 2 partials (field-wise; exact int unbias via deg) + fp32 self;
// fused W1 + ReLU + W2 -> zp: PRE-PACKED u64 {2x32b biased fixed point}.
__global__ void z_epilogue_kernel(const unsigned long long* __restrict__ partial1,
                                  const float* __restrict__ x, const int* __restrict__ degA,
                                  const float* __restrict__ W1, const float* __restrict__ b1,
                                  const float* __restrict__ W2,
                                  unsigned long long* __restrict__ zp, int N) {
    int i = blockIdx.x * blockDim.x + threadIdx.x;
    if (i >= N) return;
    unsigned long long q = ntload_u64(&partial1[i]) + ntload_u64(&partial1[(size_t)N + i]);
    int deg = ntload_i(&degA[i]);
    float di = rsqrtf((float)(deg + 1));
    int bias = deg * B1;                       // <= 45*2^14 < 2^20, exact
    int f0 = (int)(unsigned)(q & FMASK);
    int f1 = (int)(unsigned)((q >> 21) & FMASK);
    int f2 = (int)(unsigned)(q >> 42);
    float x0 = x[3 * i], x1 = x[3 * i + 1], x2 = x[3 * i + 2];
    float s0 = ((float)(f0 - bias) * IS1F + x0 * di) * di;
    float s1 = ((float)(f1 - bias) * IS1F + x1 * di) * di;
    float s2 = ((float)(f2 - bias) * IS1F + x2 * di) * di;
    float m0 = 0.f, m1 = 0.f;
#pragma unroll
    for (int k = 0; k < 8; ++k) {
        float h = fmaxf(s0 * W1[k] + s1 * W1[8 + k] + s2 * W1[16 + k] + b1[k], 0.0f);
        m0 += h * W2[2 * k];
        m1 += h * W2[2 * k + 1];
    }
    float z0 = fminf(fmaxf(m0 * di, -CLV2), CLV2);
    float z1 = fminf(fmaxf(m1 * di, -CLV2), CLV2);
    unsigned e0 = (unsigned)(__float2int_rn(z0 * S2F) + BI2);
    unsigned e1 = (unsigned)(__float2int_rn(z1 * S2F) + BI2);
    zp[i] = ((unsigned long long)e1 << 32) | e0;
}

// F1: split-K LDS accumulation of PRE-PACKED zp[src]: ONE ds_add_u64 per
// edge, zero per-edge encode VALU (2x32-bit biased fields, carry-free:
// max field sum <= 45 * (2^22 + 15*2^17) ~ 277M < 2^31).
__global__ __launch_bounds__(AGG_THREADS) void agg2_partial_kernel(
        const unsigned int* __restrict__ sorted,
        const int* __restrict__ bucketPtr,
        const unsigned long long* __restrict__ zp,
        unsigned long long* __restrict__ p2, int N) {
    __shared__ unsigned long long a01[BSZ];    // 16KB
    int t = threadIdx.x;
    int bk = blockIdx.x >> 1, sp = blockIdx.x & 1;
    for (int l = t; l < BSZ; l += AGG_THREADS) a01[l] = 0ULL;
    __syncthreads();
    int beg = bucketPtr[bk], end = bucketPtr[bk + 1], len = end - beg;
    int s0 = beg + (int)(((long long)len * sp) >> 1);
    int s1 = beg + (int)(((long long)len * (sp + 1)) >> 1);
    for (int j = s0 + t; j < s1; j += AGG_THREADS) {
        unsigned int rec = ntload_u(&sorted[j]);
        int s = rec >> SHIFT;
        int ld = rec & (BSZ - 1);
        atomicAdd(&a01[ld], zp[s]);            // ONE ds_add_u64 per edge
    }
    __syncthreads();
    size_t base = (size_t)sp * N;
    for (int l = t; l < BSZ; l += AGG_THREADS) {
        int i = (bk << SHIFT) + l;
        if (i < N) ntstore_u64(a01[l], &p2[base + i]);
    }
}

// F2: decode 2 partials + self (from zp, exact int fields) -> out.
__global__ void out_epilogue_kernel(const unsigned long long* __restrict__ p2,
                                    const unsigned long long* __restrict__ zp,
                                    const int* __restrict__ degA,
                                    const float* __restrict__ b2, float* __restrict__ out, int N) {
    int i = blockIdx.x * blockDim.x + threadIdx.x;
    if (i >= N) return;
    unsigned long long q = ntload_u64(&p2[i]) + ntload_u64(&p2[(size_t)N + i]);
    int deg = ntload_i(&degA[i]);
    float di = rsqrtf((float)(deg + 1));
    int bias = deg * BI2;
    float sum0 = (float)((int)(unsigned)q - bias) * IS2F;
    float sum1 = (float)((int)(unsigned)(q >> 32) - bias) * IS2F;
    unsigned long long zs = zp[i];
    float zs0 = (float)((int)(unsigned)zs - BI2) * IS2F;
    float zs1 = (float)((int)(unsigned)(zs >> 32) - BI2) * IS2F;
    out[(size_t)i * 2]     = di * (sum0 + zs0) + b2[0];
    out[(size_t)i * 2 + 1] = di * (sum1 + zs1) + b2[1];
}

extern "C" void kernel_launch(void* const* d_in, const int* in_sizes, int n_in,
                              void* d_out, int out_size, void* d_ws, size_t ws_size,
                              hipStream_t stream) {
    const float* x  = (const float*)d_in[0];
    const int*   ei = (const int*)d_in[1];   // [2, E] flat: src row, dst row
    const float* W1 = (const float*)d_in[2];
    const float* b1 = (const float*)d_in[3];
    const float* W2 = (const float*)d_in[4];
    const float* b2 = (const float*)d_in[5];
    float* out = (float*)d_out;

    const int N = in_sizes[0] / 3;
    const int E = in_sizes[1] / 2;
    const int NBK = (N + BSZ - 1) / BSZ;       // 245 buckets
    const int NBA = (E + CH - 1) / CH;         // 245 blocks in A/C

    // Workspace. `scratch` reused sequentially: partialD (D1->D2), then
    // partial1 (E1->E2), then p2 (F1->F2). All bytes written before read.
    char* ws = (char*)d_ws;
    size_t off = 0;
    auto alloc = [&](size_t bytes) { char* p = ws + off; off = (off + bytes + 15) & ~(size_t)15; return p; };
    int* histM           = (int*)alloc((size_t)NBK * NBA * 4);
    int* totals          = (int*)alloc((size_t)NBK * 4);
    int* bucketPtr       = (int*)alloc(((size_t)NBK + 1) * 4);
    char* scratch        = alloc((size_t)SPLIT * N * 16);
    int* degA            = (int*)alloc((size_t)N * 4);
    unsigned long long* zp  = (unsigned long long*)alloc((size_t)N * 8);
    unsigned long long* thp = (unsigned long long*)alloc((size_t)N * 8);
    unsigned int* sorted = (unsigned int*)alloc((size_t)E * 4);
    (void)ws_size;

    int* partialD             = (int*)scratch;                    // SPLIT*N*4
    unsigned long long* partial1 = (unsigned long long*)scratch;  // SPLIT*N*8
    unsigned long long* p2    = (unsigned long long*)scratch;     // SPLIT*N*8

    const int nb = (N + 255) / 256;

    bucket_count_kernel<<<NBA, AC_THREADS, 0, stream>>>(ei + E, histM, E, NBA, NBK);
    colscan_kernel<<<NBK, 256, 0, stream>>>(histM, totals, NBA);
    bucketscan_kernel<<<1, 256, 0, stream>>>(totals, bucketPtr, NBK, E);
    bucket_scatter_kernel<<<NBA, AC_THREADS, 0, stream>>>(ei, histM, bucketPtr, sorted, E, NBA, NBK);
    deg_partial_kernel<<<NBK * SPLIT, AGG_THREADS, 0, stream>>>(sorted, bucketPtr, partialD, N);
    deg_xd_kernel<<<nb, 256, 0, stream>>>(partialD, x, degA, thp, N);
    agg1_partial_kernel<<<NBK * SPLIT, AGG_THREADS, 0, stream>>>(sorted, bucketPtr, thp, partial1, N);
    z_epilogue_kernel<<<nb, 256, 0, stream>>>(partial1, x, degA, W1, b1, W2, zp, N);
    agg2_partial_kernel<<<NBK * SPLIT, AGG_THREADS, 0, stream>>>(sorted, bucketPtr, zp, p2, N);
    out_epilogue_kernel<<<nb, 256, 0, stream>>>(p2, zp, degA, b2, out, N);
}